// Round 16
// baseline (1315.046 us; speedup 1.0000x reference)
//
#include <hip/hip_runtime.h>

// N=100000 nodes, E=1600000 edges, IN=128, H=64, R=32, B=512
constexpr int HD     = 64;
constexpr int RNUM   = 32;
constexpr int STRIDE = 200;   // target edges per fused block
constexpr int CAPE   = 216;   // LDS msg rows; ~31 KB LDS -> 5 blocks/CU

typedef __attribute__((ext_vector_type(4))) float f32x4;
typedef __attribute__((ext_vector_type(8))) short bf16x8;

#define WS_ALIGN(x) (((x) + size_t(255)) & ~size_t(255))

__device__ inline float b2f(unsigned short u) {
    return __uint_as_float(((unsigned)u) << 16);
}
__device__ inline unsigned short f2b(float f) {
    unsigned u = __float_as_uint(f);
    u = (u + 0x7FFF + ((u >> 16) & 1)) >> 16;
    return (unsigned short)u;
}
__device__ inline unsigned pack2bf(float a, float b) {
    return (unsigned)f2b(a) | ((unsigned)f2b(b) << 16);
}

// ---------------- preprocessing ----------------

__global__ __launch_bounds__(256) void count_kernel(
    const int* __restrict__ dst, int* __restrict__ deg, int* __restrict__ rank, int E)
{
    int e = blockIdx.x * 256 + threadIdx.x;
    if (e < E) rank[e] = atomicAdd(&deg[dst[e]], 1);
}

__global__ __launch_bounds__(256) void scan1_kernel(
    const int* __restrict__ in, int* __restrict__ out, int* __restrict__ part, int n)
{
    __shared__ int ls[256];
    const int i0 = blockIdx.x * 1024 + threadIdx.x * 4;
    int v[4];
    int tot = 0;
#pragma unroll
    for (int u = 0; u < 4; ++u) {
        int x = (i0 + u < n) ? in[i0 + u] : 0;
        v[u] = tot;
        tot += x;
    }
    ls[threadIdx.x] = tot;
    __syncthreads();
    for (int off = 1; off < 256; off <<= 1) {
        int x = (threadIdx.x >= off) ? ls[threadIdx.x - off] : 0;
        __syncthreads();
        ls[threadIdx.x] += x;
        __syncthreads();
    }
    int texcl = ls[threadIdx.x] - tot;
#pragma unroll
    for (int u = 0; u < 4; ++u)
        if (i0 + u < n) out[i0 + u] = texcl + v[u];
    if (threadIdx.x == 255) part[blockIdx.x] = ls[255];
}

__global__ void scan2_kernel(int* __restrict__ part, int nb, int* __restrict__ out, int n)
{
    if (threadIdx.x == 0) {
        int acc = 0;
        for (int i = 0; i < nb; ++i) { int t = part[i]; part[i] = acc; acc += t; }
        out[n] = acc;
    }
}

__global__ __launch_bounds__(256) void scan3_kernel(
    int* __restrict__ out, const int* __restrict__ part, int n)
{
    int i = blockIdx.x * 256 + threadIdx.x;
    if (i < n) out[i] += part[blockIdx.x >> 2];
}

// bstart[b] = first node n with nstart[n] >= b*STRIDE
__global__ __launch_bounds__(256) void boundary_kernel(
    const int* __restrict__ nstart, int* __restrict__ bstart, int N, int nblk)
{
    int b = blockIdx.x * 256 + threadIdx.x;
    if (b > nblk) return;
    if (b == nblk) { bstart[b] = N; return; }
    int target = b * STRIDE;
    int lo = 0, hi = N;
    while (lo < hi) {
        int mid = (lo + hi) >> 1;
        if (nstart[mid] < target) lo = mid + 1; else hi = mid;
    }
    bstart[b] = lo;
}

// CSR scatter: es[nstart[d]+rank[e]] = src | (type<<17)
__global__ __launch_bounds__(256) void scatter_kernel(
    const int* __restrict__ src, const int* __restrict__ dst, const int* __restrict__ et,
    const int* __restrict__ rank, const int* __restrict__ nstart,
    int* __restrict__ es, int E)
{
    int e = blockIdx.x * 256 + threadIdx.x;
    if (e < E)
        es[nstart[dst[e]] + rank[e]] = src[e] | (et[e] << 17);
}

__global__ __launch_bounds__(256) void tobf16_kernel(
    const float* __restrict__ in, unsigned short* __restrict__ out, int total8)
{
    int i = blockIdx.x * 256 + threadIdx.x;
    if (i >= total8) return;
    const float4* ip = (const float4*)(in + (size_t)i * 8);
    float4 a = ip[0], b = ip[1];
    uint4 o;
    o.x = pack2bf(a.x, a.y); o.y = pack2bf(a.z, a.w);
    o.z = pack2bf(b.x, b.y); o.w = pack2bf(b.z, b.w);
    *(uint4*)(out + (size_t)i * 8) = o;
}

// pre-permute W (32 relations) into MFMA A-fragment layout, bf16
template<int K>
__global__ __launch_bounds__(256) void wfrag_kernel(
    const float* __restrict__ W, unsigned short* __restrict__ wfrag)
{
    constexpr int KS = K / 32;
    int idx = blockIdx.x * 256 + threadIdx.x;
    int total = RNUM * KS * 4 * 64;
    if (idx >= total) return;
    int lane = idx & 63;
    int tmp = idx >> 6;
    int jt = tmp & 3; tmp >>= 2;
    int ks = tmp % KS;
    int t = tmp / KS;
    int col = jt * 16 + (lane & 15);
    int kb = ks * 32 + (lane >> 4) * 8;
    const float* Wp = W + ((size_t)t * K + kb) * HD + col;
    uint4 o;
    o.x = pack2bf(Wp[0 * HD], Wp[1 * HD]);
    o.y = pack2bf(Wp[2 * HD], Wp[3 * HD]);
    o.z = pack2bf(Wp[4 * HD], Wp[5 * HD]);
    o.w = pack2bf(Wp[6 * HD], Wp[7 * HD]);
    *(uint4*)(wfrag + (size_t)idx * 8) = o;
}

// same fragment permute for a single matrix (Wroot)
template<int K>
__global__ __launch_bounds__(256) void wfroot_kernel(
    const float* __restrict__ Root, unsigned short* __restrict__ wfr)
{
    constexpr int KS = K / 32;
    int idx = blockIdx.x * 256 + threadIdx.x;
    int total = KS * 4 * 64;
    if (idx >= total) return;
    int lane = idx & 63;
    int tmp = idx >> 6;
    int jt = tmp & 3;
    int ks = tmp >> 2;
    int col = jt * 16 + (lane & 15);
    int kb = ks * 32 + (lane >> 4) * 8;
    const float* Wp = Root + (size_t)kb * HD + col;
    uint4 o;
    o.x = pack2bf(Wp[0 * HD], Wp[1 * HD]);
    o.y = pack2bf(Wp[2 * HD], Wp[3 * HD]);
    o.z = pack2bf(Wp[4 * HD], Wp[5 * HD]);
    o.w = pack2bf(Wp[6 * HD], Wp[7 * HD]);
    *(uint4*)(wfr + (size_t)idx * 8) = o;
}

// dense MFMA GEMM: hroot[n][j] = bias[j] + sum_k x[n][k]*Root[k][j]  (bf16 out)
template<int K>
__global__ __launch_bounds__(256) void rootmm_kernel(
    const unsigned short* __restrict__ xb, const unsigned short* __restrict__ wfr,
    const float* __restrict__ bias, unsigned short* __restrict__ hroot, int N)
{
    constexpr int KS = K / 32;
    __shared__ unsigned short sW[KS * 4 * 64 * 8];
    __shared__ float sbias[HD];
    const int tid = threadIdx.x;
    for (int i = tid; i < KS * 256; i += 256)
        ((uint4*)sW)[i] = ((const uint4*)wfr)[i];
    if (tid < HD) sbias[tid] = bias[tid];
    __syncthreads();
    const int lane = tid & 63;
    const int wid = tid >> 6;
    const int jb = (lane >> 4) * 4;
#pragma unroll
    for (int b = 0; b < 4; ++b) {
        const int node = blockIdx.x * 256 + wid * 64 + b * 16 + (lane & 15);
        const int nclamp = node < N ? node : N - 1;
        const unsigned short* xp = xb + (size_t)nclamp * K + (lane >> 4) * 8;
        f32x4 acc[4];
#pragma unroll
        for (int jt = 0; jt < 4; ++jt) acc[jt] = (f32x4)0.0f;
#pragma unroll
        for (int ks = 0; ks < KS; ++ks) {
            bf16x8 bx = *(const bf16x8*)(xp + ks * 32);
#pragma unroll
            for (int jt = 0; jt < 4; ++jt) {
                bf16x8 aw = *(const bf16x8*)(sW + (size_t)((ks * 4 + jt) * 64 + lane) * 8);
                acc[jt] = __builtin_amdgcn_mfma_f32_16x16x32_bf16(aw, bx, acc[jt], 0, 0, 0);
            }
        }
        if (node < N) {
            unsigned short* hr = hroot + (size_t)node * HD + jb;
#pragma unroll
            for (int jt = 0; jt < 4; ++jt) {
                const int j0 = jt * 16 + jb;
                uint2 pk;
                pk.x = pack2bf(acc[jt][0] + sbias[j0 + 0], acc[jt][1] + sbias[j0 + 1]);
                pk.y = pack2bf(acc[jt][2] + sbias[j0 + 2], acc[jt][3] + sbias[j0 + 3]);
                *(uint2*)(hr + jt * 16) = pk;
            }
        }
    }
}

// fused RGCN layer: 256 threads, ~31 KB LDS -> 5 blocks/CU (20 waves).
// Node-aligned window, in-LDS type sort (wave-parallel setup), depth-1
// gather pipeline, msg at sorted position (XOR swizzle), per-node segmented
// mean + hroot + relu. PL=1: layer-2 variant, fuses global mean-pool
// (run-accumulate per contiguous node range, atomic flush per graph) and
// skips the h write entirely.
template<int K, int PL>
__global__ __launch_bounds__(256) void fused_kernel(
    const unsigned short* __restrict__ xb, const int* __restrict__ es,
    const int* __restrict__ nstart, const int* __restrict__ bstart,
    const unsigned short* __restrict__ wfrag,
    const unsigned short* __restrict__ hroot,
    unsigned short* __restrict__ hout,
    const int* __restrict__ batch, float* __restrict__ pool,
    float* __restrict__ gcnt, int col0)
{
    constexpr int KS = K / 32;
    __shared__ unsigned short msg[CAPE * HD];
    __shared__ int s_es[CAPE];
    __shared__ unsigned short s_idx[CAPE];      // sorted pos -> orig idx
    __shared__ unsigned short s_pos[CAPE];      // orig idx -> sorted pos
    __shared__ int hist[RNUM], tbase[RNUM], tcur[RNUM];
    __shared__ int bdesc[CAPE / 16 + RNUM + 2];
    __shared__ int nb_s, nend_s;
    __shared__ int scnt[4][RNUM];
    __shared__ float sinv[4][RNUM];

    const int tid = threadIdx.x, lane = tid & 63, wid = tid >> 6;
    int n0 = bstart[blockIdx.x];
    const int n1 = bstart[blockIdx.x + 1];

    while (n0 < n1) {
        // wave-0 cooperative greedy pack: nodes [n0, nend) with <= CAPE edges
        if (wid == 0) {
            const int ea_ = nstart[n0];
            int m = n0;
            for (;;) {
                int cand = m + 1 + lane;
                bool ok = (cand <= n1) && (nstart[cand] - ea_ <= CAPE);
                unsigned long long mm = __ballot(ok);
                int f = (~mm == 0ULL) ? 64 : (__ffsll((unsigned long long)(~mm)) - 1);
                m += f;
                if (f < 64 || m >= n1) break;
            }
            if (m == n0) m = n0 + 1;          // single node with deg > CAPE: clamp
            if (m > n1) m = n1;
            if (lane == 0) nend_s = m;
        }
        __syncthreads();
        const int na = n0, ne = nend_s;
        const int ea = nstart[na];
        int cnt = nstart[ne] - ea;
        if (cnt > CAPE) cnt = CAPE;

        // stage + type counting sort (int LDS atomics only)
        for (int i = tid; i < cnt; i += 256) s_es[i] = es[ea + i];
        if (tid < RNUM) hist[tid] = 0;
        __syncthreads();
        for (int i = tid; i < cnt; i += 256)
            atomicAdd(&hist[(s_es[i] >> 17) & 31], 1);
        __syncthreads();
        // wave-parallel tbase + bdesc build (lanes 0..31 of wave 0)
        if (wid == 0) {
            const int t = lane & 31;
            int h = (lane < RNUM) ? hist[t] : 0;
            int nbatch = (h + 15) >> 4;
            int ph = h, pb = nbatch;
            for (int off = 1; off < 32; off <<= 1) {
                int vh = __shfl_up(ph, off, 32);
                int vb = __shfl_up(pb, off, 32);
                if ((lane & 31) >= off) { ph += vh; pb += vb; }
            }
            if (lane < RNUM) {
                const int tb = ph - h;
                tbase[t] = tb;
                int bo = pb - nbatch;
                for (int c2 = 0; c2 < h; c2 += 16)
                    bdesc[bo++] = (t << 10) | (tb + c2);
                if (t == RNUM - 1) nb_s = pb;
            }
        }
        __syncthreads();
        if (tid < RNUM) tcur[tid] = tbase[tid];
        __syncthreads();
        for (int i = tid; i < cnt; i += 256) {
            int t = (s_es[i] >> 17) & 31;
            int pos = atomicAdd(&tcur[t], 1);
            s_idx[pos] = (unsigned short)i;
            s_pos[i] = (unsigned short)pos;
        }
        __syncthreads();

        // MFMA phase: 16-edge single-type batches, depth-1 prefetch pipeline
        {
            const int nbt = nb_s;
            const int b0 = (nbt * wid) >> 2;
            const int b1 = (nbt * (wid + 1)) >> 2;
            if (b0 < b1) {
                int c_c;
                bool val_c;
                const unsigned short* wt_c;
                bf16x8 bx_c[KS];
                {
                    const int desc = bdesc[b0];
                    const int t = desc >> 10;
                    const int p0 = desc & 1023;
                    const int tend = tbase[t] + hist[t];
                    c_c = p0 + (lane & 15);
                    val_c = c_c < tend;
                    wt_c = wfrag + (size_t)t * (KS * 2048);
                    const int idx = s_idx[val_c ? c_c : p0];
                    const unsigned short* xp =
                        xb + (size_t)(s_es[idx] & 0x1FFFF) * K + (lane >> 4) * 8;
#pragma unroll
                    for (int ks = 0; ks < KS; ++ks) bx_c[ks] = *(const bf16x8*)(xp + ks * 32);
                }
                for (int bi = b0; bi < b1; ++bi) {
                    int c_n = 0;
                    bool val_n = false;
                    const unsigned short* wt_n = wt_c;
                    bf16x8 bx_n[KS];
                    if (bi + 1 < b1) {
                        const int desc = bdesc[bi + 1];
                        const int t = desc >> 10;
                        const int p0 = desc & 1023;
                        const int tend = tbase[t] + hist[t];
                        c_n = p0 + (lane & 15);
                        val_n = c_n < tend;
                        wt_n = wfrag + (size_t)t * (KS * 2048);
                        const int idx = s_idx[val_n ? c_n : p0];
                        const unsigned short* xp =
                            xb + (size_t)(s_es[idx] & 0x1FFFF) * K + (lane >> 4) * 8;
#pragma unroll
                        for (int ks = 0; ks < KS; ++ks) bx_n[ks] = *(const bf16x8*)(xp + ks * 32);
                    }
                    f32x4 acc[4];
#pragma unroll
                    for (int jt = 0; jt < 4; ++jt) acc[jt] = (f32x4)0.0f;
#pragma unroll
                    for (int ks = 0; ks < KS; ++ks) {
#pragma unroll
                        for (int jt = 0; jt < 4; ++jt) {
                            bf16x8 aw = *(const bf16x8*)(wt_c + (size_t)((ks * 4 + jt) * 64 + lane) * 8);
                            acc[jt] = __builtin_amdgcn_mfma_f32_16x16x32_bf16(aw, bx_c[ks], acc[jt], 0, 0, 0);
                        }
                    }
                    if (val_c) {
                        char* mr = (char*)(msg + c_c * HD);
                        const int swz = (c_c & 7) << 4;
#pragma unroll
                        for (int jt = 0; jt < 4; ++jt) {
                            uint2 pk;
                            pk.x = pack2bf(acc[jt][0], acc[jt][1]);
                            pk.y = pack2bf(acc[jt][2], acc[jt][3]);
                            *(uint2*)(mr + (((lane >> 4) * 8 + jt * 32) ^ swz)) = pk;
                        }
                    }
                    c_c = c_n; val_c = val_n; wt_c = wt_n;
#pragma unroll
                    for (int ks = 0; ks < KS; ++ks) bx_c[ks] = bx_n[ks];
                }
            }
        }
        __syncthreads();

        // reduce phase
        if (PL) {
            // contiguous node range per wave; run-accumulate pool (batch sorted)
            const int NL = ne - na;
            const int ns = na + (NL * wid) / 4;
            const int nf = na + (NL * (wid + 1)) / 4;
            if (ns < nf) {
                int cur = batch[ns];
                float pacc = 0.f, pc = 0.f;
                for (int n = ns; n < nf; ++n) {
                    const int rs = nstart[n] - ea;
                    int re = nstart[n + 1] - ea;
                    if (re > cnt) re = cnt;
                    if (lane < RNUM) scnt[wid][lane] = 0;
                    for (int e = rs + lane; e < re; e += 64)
                        atomicAdd(&scnt[wid][(s_es[e] >> 17) & 31], 1);
                    if (lane < RNUM) {
                        int c = scnt[wid][lane];
                        sinv[wid][lane] = 1.0f / (float)(c > 1 ? c : 1);
                    }
                    float acc = b2f(hroot[(size_t)n * HD + lane]);
                    for (int e = rs; e < re; ++e) {
                        const float iv = sinv[wid][(s_es[e] >> 17) & 31];
                        const int row = s_pos[e];
                        const char* mr = (const char*)(msg + row * HD);
                        acc += iv * b2f(*(const unsigned short*)(mr + ((lane * 2) ^ ((row & 7) << 4))));
                    }
                    float rv = fmaxf(acc, 0.f);
                    int b = batch[n];
                    if (b != cur) {
                        unsafeAtomicAdd(&pool[(size_t)cur * 128 + col0 + lane], pacc);
                        if (lane == 0) unsafeAtomicAdd(&gcnt[cur], pc);
                        pacc = 0.f; pc = 0.f; cur = b;
                    }
                    pacc += rv;
                    pc += 1.f;
                }
                unsafeAtomicAdd(&pool[(size_t)cur * 128 + col0 + lane], pacc);
                if (lane == 0) unsafeAtomicAdd(&gcnt[cur], pc);
            }
        } else {
            for (int n = na + wid; n < ne; n += 4) {
                const int rs = nstart[n] - ea;
                int re = nstart[n + 1] - ea;
                if (re > cnt) re = cnt;
                if (lane < RNUM) scnt[wid][lane] = 0;
                for (int e = rs + lane; e < re; e += 64)
                    atomicAdd(&scnt[wid][(s_es[e] >> 17) & 31], 1);
                if (lane < RNUM) {
                    int c = scnt[wid][lane];
                    sinv[wid][lane] = 1.0f / (float)(c > 1 ? c : 1);
                }
                float acc = b2f(hroot[(size_t)n * HD + lane]);
                for (int e = rs; e < re; ++e) {
                    const float iv = sinv[wid][(s_es[e] >> 17) & 31];
                    const int row = s_pos[e];
                    const char* mr = (const char*)(msg + row * HD);
                    acc += iv * b2f(*(const unsigned short*)(mr + ((lane * 2) ^ ((row & 7) << 4))));
                }
                hout[(size_t)n * HD + lane] = f2b(fmaxf(acc, 0.f));
            }
        }
        __syncthreads();
        n0 = ne;
    }
}

__global__ __launch_bounds__(512) void depth_kernel(
    const float* __restrict__ depth, float* __restrict__ dnorm, int Bn)
{
    __shared__ float ls[8];
    __shared__ float smean, sstd;
    const int t = threadIdx.x, lane = t & 63, wv = t >> 6;
    float d = (t < Bn) ? depth[t] : 0.f;
    float s = d;
#pragma unroll
    for (int o = 32; o; o >>= 1) s += __shfl_down(s, o, 64);
    if (lane == 0) ls[wv] = s;
    __syncthreads();
    if (t == 0) {
        float tot = 0.f;
        for (int i = 0; i < 8; ++i) tot += ls[i];
        smean = tot / (float)Bn;
    }
    __syncthreads();
    float mean = smean;
    float df = (t < Bn) ? (d - mean) : 0.f;
    s = df * df;
#pragma unroll
    for (int o = 32; o; o >>= 1) s += __shfl_down(s, o, 64);
    __syncthreads();
    if (lane == 0) ls[wv] = s;
    __syncthreads();
    if (t == 0) {
        float tot = 0.f;
        for (int i = 0; i < 8; ++i) tot += ls[i];
        sstd = sqrtf(tot / (float)Bn);
    }
    __syncthreads();
    if (t < Bn) dnorm[t] = df / (sstd + 1e-6f);
}

__global__ __launch_bounds__(256) void regress_kernel(
    const float* __restrict__ pool, const float* __restrict__ gcnt_s,
    const float* __restrict__ gcnt_g, const float* __restrict__ dnorm,
    const float* __restrict__ rW1, const float* __restrict__ rB1,
    const float* __restrict__ rW2, const float* __restrict__ rB2,
    float* __restrict__ pred, int Bn)
{
    const int lane = threadIdx.x & 63;
    const int g = (blockIdx.x * 256 + threadIdx.x) >> 6;
    if (g >= Bn) return;
    const float is = 1.f / fmaxf(gcnt_s[g], 1.f);
    const float ig = 1.f / fmaxf(gcnt_g[g], 1.f);
    const float* pr = pool + (size_t)g * 128;
    float acc = rB1[lane];
    for (int k = 0; k < 64; ++k)
        acc = fmaf(pr[k] * is, rW1[k * 64 + lane], acc);
    for (int k = 64; k < 128; ++k)
        acc = fmaf(pr[k] * ig, rW1[k * 64 + lane], acc);
    acc = fmaf(dnorm[g], rW1[128 * 64 + lane], acc);
    float v = fmaxf(acc, 0.f) * rW2[lane];
#pragma unroll
    for (int o = 32; o; o >>= 1) v += __shfl_down(v, o, 64);
    if (lane == 0) pred[g] = v + rB2[0];
}

// ---------------- launch ----------------

extern "C" void kernel_launch(void* const* d_in, const int* in_sizes, int n_in,
                              void* d_out, int out_size, void* d_ws, size_t ws_size,
                              hipStream_t stream)
{
    const int E1 = in_sizes[2];
    const int E2 = in_sizes[6];
    const int Emax = E1 > E2 ? E1 : E2;
    const int N = in_sizes[3];
    const int IN = in_sizes[0] / N;   // 128
    const int Bn = in_sizes[8];

    const float* state_x = (const float*)d_in[0];
    const int* s_ei = (const int*)d_in[1];
    const int* s_et = (const int*)d_in[2];
    const int* s_batch = (const int*)d_in[3];
    const float* goal_x = (const float*)d_in[4];
    const int* g_ei = (const int*)d_in[5];
    const int* g_et = (const int*)d_in[6];
    const int* g_batch = (const int*)d_in[7];
    const float* depth = (const float*)d_in[8];
    const float* sW1 = (const float*)d_in[9];
    const float* sRoot1 = (const float*)d_in[10];
    const float* sB1 = (const float*)d_in[11];
    const float* sW2 = (const float*)d_in[12];
    const float* sRoot2 = (const float*)d_in[13];
    const float* sB2 = (const float*)d_in[14];
    const float* gW1 = (const float*)d_in[15];
    const float* gRoot1 = (const float*)d_in[16];
    const float* gB1 = (const float*)d_in[17];
    const float* gW2 = (const float*)d_in[18];
    const float* gRoot2 = (const float*)d_in[19];
    const float* gB2 = (const float*)d_in[20];
    const float* rW1 = (const float*)d_in[21];
    const float* rB1 = (const float*)d_in[22];
    const float* rW2 = (const float*)d_in[23];
    const float* rB2 = (const float*)d_in[24];
    float* pred = (float*)d_out;

    const int nbScan = (N + 1023) / 1024;
    const int nblkMax = (Emax + STRIDE - 1) / STRIDE;

    char* p = (char*)d_ws;
    auto alloc = [&](size_t bytes) { char* r = p; p += WS_ALIGN(bytes); return r; };
    int* deg    = (int*)alloc((size_t)N * 4);
    int* nstart = (int*)alloc((size_t)(N + 1) * 4);
    int* rank   = (int*)alloc((size_t)Emax * 4);
    int* part   = (int*)alloc((size_t)nbScan * 4);
    int* bstart = (int*)alloc((size_t)(nblkMax + 1) * 4);
    int* es     = (int*)alloc((size_t)Emax * 4);
    unsigned short* xb    = (unsigned short*)alloc((size_t)N * IN * 2);
    unsigned short* h1    = (unsigned short*)alloc((size_t)N * HD * 2);
    unsigned short* hroot = (unsigned short*)alloc((size_t)N * HD * 2);
    unsigned short* wf1   = (unsigned short*)alloc((size_t)RNUM * 4 * 4 * 64 * 8 * 2);
    unsigned short* wf2   = (unsigned short*)alloc((size_t)RNUM * 2 * 4 * 64 * 8 * 2);
    unsigned short* wfr1  = (unsigned short*)alloc((size_t)4 * 4 * 64 * 8 * 2);
    unsigned short* wfr2  = (unsigned short*)alloc((size_t)2 * 4 * 64 * 8 * 2);
    float* pool   = (float*)alloc((size_t)Bn * 128 * 4);
    float* gcnt_s = (float*)alloc((size_t)Bn * 4);
    float* gcnt_g = (float*)alloc((size_t)Bn * 4);
    float* dnorm  = (float*)alloc((size_t)Bn * 4);

    hipMemsetAsync(pool, 0, (size_t)Bn * 128 * 4, stream);
    hipMemsetAsync(gcnt_s, 0, (size_t)Bn * 4, stream);
    hipMemsetAsync(gcnt_g, 0, (size_t)Bn * 4, stream);

    const int nmmB = (N + 255) / 256;

    for (int enc = 0; enc < 2; ++enc) {
        const float* x = enc ? goal_x : state_x;
        const int* ei = enc ? g_ei : s_ei;
        const int* et = enc ? g_et : s_et;
        const int* batch = enc ? g_batch : s_batch;
        const float* W1 = enc ? gW1 : sW1;
        const float* Root1 = enc ? gRoot1 : sRoot1;
        const float* B1 = enc ? gB1 : sB1;
        const float* W2 = enc ? gW2 : sW2;
        const float* Root2 = enc ? gRoot2 : sRoot2;
        const float* B2 = enc ? gB2 : sB2;
        float* gcnt = enc ? gcnt_g : gcnt_s;
        const int E = enc ? E2 : E1;
        const int* srcp = ei;
        const int* dstp = ei + E;
        const int ebl = (E + 255) / 256;
        const int nblk = (E + STRIDE - 1) / STRIDE;

        hipMemsetAsync(deg, 0, (size_t)N * 4, stream);

        count_kernel<<<ebl, 256, 0, stream>>>(dstp, deg, rank, E);
        scan1_kernel<<<nbScan, 256, 0, stream>>>(deg, nstart, part, N);
        scan2_kernel<<<1, 64, 0, stream>>>(part, nbScan, nstart, N);
        scan3_kernel<<<nbScan * 4, 256, 0, stream>>>(nstart, part, N);
        boundary_kernel<<<(nblk + 1 + 255) / 256, 256, 0, stream>>>(nstart, bstart, N, nblk);
        scatter_kernel<<<ebl, 256, 0, stream>>>(srcp, dstp, et, rank, nstart, es, E);

        tobf16_kernel<<<(N * IN / 8 + 255) / 256, 256, 0, stream>>>(x, xb, N * IN / 8);
        wfrag_kernel<128><<<(RNUM * 4 * 4 * 64 + 255) / 256, 256, 0, stream>>>(W1, wf1);
        wfrag_kernel<64><<<(RNUM * 2 * 4 * 64 + 255) / 256, 256, 0, stream>>>(W2, wf2);
        wfroot_kernel<128><<<(4 * 4 * 64 + 255) / 256, 256, 0, stream>>>(Root1, wfr1);
        wfroot_kernel<64><<<(2 * 4 * 64 + 255) / 256, 256, 0, stream>>>(Root2, wfr2);

        // layer 1
        rootmm_kernel<128><<<nmmB, 256, 0, stream>>>(xb, wfr1, B1, hroot, N);
        fused_kernel<128, 0><<<nblk, 256, 0, stream>>>(
            xb, es, nstart, bstart, wf1, hroot, h1, nullptr, nullptr, nullptr, 0);
        // layer 2 (pool fused; no h2 write)
        rootmm_kernel<64><<<nmmB, 256, 0, stream>>>(h1, wfr2, B2, hroot, N);
        fused_kernel<64, 1><<<nblk, 256, 0, stream>>>(
            h1, es, nstart, bstart, wf2, hroot, nullptr, batch, pool, gcnt, enc * 64);
    }

    depth_kernel<<<1, 512, 0, stream>>>(depth, dnorm, Bn);
    regress_kernel<<<(Bn * 64 + 255) / 256, 256, 0, stream>>>(
        pool, gcnt_s, gcnt_g, dnorm, rW1, rB1, rW2, rB2, pred, Bn);
}

// Round 17
// 1197.277 us; speedup vs baseline: 1.0984x; 1.0984x over previous
//
#include <hip/hip_runtime.h>

// N=100000 nodes, E=1600000 edges, IN=128, H=64, R=32, B=512
constexpr int HD     = 64;
constexpr int RNUM   = 32;
constexpr int STRIDE = 256;   // target edges per fused block
constexpr int CAPE   = 280;   // LDS msg rows; ~40 KB LDS -> 4 blocks/CU

typedef __attribute__((ext_vector_type(4))) float f32x4;
typedef __attribute__((ext_vector_type(8))) short bf16x8;

#define WS_ALIGN(x) (((x) + size_t(255)) & ~size_t(255))

__device__ inline float b2f(unsigned short u) {
    return __uint_as_float(((unsigned)u) << 16);
}
__device__ inline unsigned short f2b(float f) {
    unsigned u = __float_as_uint(f);
    u = (u + 0x7FFF + ((u >> 16) & 1)) >> 16;
    return (unsigned short)u;
}
__device__ inline unsigned pack2bf(float a, float b) {
    return (unsigned)f2b(a) | ((unsigned)f2b(b) << 16);
}

// ---------------- preprocessing ----------------

__global__ __launch_bounds__(256) void count_kernel(
    const int* __restrict__ dst, int* __restrict__ deg, int* __restrict__ rank, int E)
{
    int e = blockIdx.x * 256 + threadIdx.x;
    if (e < E) rank[e] = atomicAdd(&deg[dst[e]], 1);
}

__global__ __launch_bounds__(256) void scan1_kernel(
    const int* __restrict__ in, int* __restrict__ out, int* __restrict__ part, int n)
{
    __shared__ int ls[256];
    const int i0 = blockIdx.x * 1024 + threadIdx.x * 4;
    int v[4];
    int tot = 0;
#pragma unroll
    for (int u = 0; u < 4; ++u) {
        int x = (i0 + u < n) ? in[i0 + u] : 0;
        v[u] = tot;
        tot += x;
    }
    ls[threadIdx.x] = tot;
    __syncthreads();
    for (int off = 1; off < 256; off <<= 1) {
        int x = (threadIdx.x >= off) ? ls[threadIdx.x - off] : 0;
        __syncthreads();
        ls[threadIdx.x] += x;
        __syncthreads();
    }
    int texcl = ls[threadIdx.x] - tot;
#pragma unroll
    for (int u = 0; u < 4; ++u)
        if (i0 + u < n) out[i0 + u] = texcl + v[u];
    if (threadIdx.x == 255) part[blockIdx.x] = ls[255];
}

__global__ void scan2_kernel(int* __restrict__ part, int nb, int* __restrict__ out, int n)
{
    if (threadIdx.x == 0) {
        int acc = 0;
        for (int i = 0; i < nb; ++i) { int t = part[i]; part[i] = acc; acc += t; }
        out[n] = acc;
    }
}

__global__ __launch_bounds__(256) void scan3_kernel(
    int* __restrict__ out, const int* __restrict__ part, int n)
{
    int i = blockIdx.x * 256 + threadIdx.x;
    if (i < n) out[i] += part[blockIdx.x >> 2];
}

// bstart[b] = first node n with nstart[n] >= b*STRIDE
__global__ __launch_bounds__(256) void boundary_kernel(
    const int* __restrict__ nstart, int* __restrict__ bstart, int N, int nblk)
{
    int b = blockIdx.x * 256 + threadIdx.x;
    if (b > nblk) return;
    if (b == nblk) { bstart[b] = N; return; }
    int target = b * STRIDE;
    int lo = 0, hi = N;
    while (lo < hi) {
        int mid = (lo + hi) >> 1;
        if (nstart[mid] < target) lo = mid + 1; else hi = mid;
    }
    bstart[b] = lo;
}

// CSR scatter: es[nstart[d]+rank[e]] = src | (type<<17)
__global__ __launch_bounds__(256) void scatter_kernel(
    const int* __restrict__ src, const int* __restrict__ dst, const int* __restrict__ et,
    const int* __restrict__ rank, const int* __restrict__ nstart,
    int* __restrict__ es, int E)
{
    int e = blockIdx.x * 256 + threadIdx.x;
    if (e < E)
        es[nstart[dst[e]] + rank[e]] = src[e] | (et[e] << 17);
}

__global__ __launch_bounds__(256) void tobf16_kernel(
    const float* __restrict__ in, unsigned short* __restrict__ out, int total8)
{
    int i = blockIdx.x * 256 + threadIdx.x;
    if (i >= total8) return;
    const float4* ip = (const float4*)(in + (size_t)i * 8);
    float4 a = ip[0], b = ip[1];
    uint4 o;
    o.x = pack2bf(a.x, a.y); o.y = pack2bf(a.z, a.w);
    o.z = pack2bf(b.x, b.y); o.w = pack2bf(b.z, b.w);
    *(uint4*)(out + (size_t)i * 8) = o;
}

// pre-permute W (32 relations) into MFMA A-fragment layout, bf16
template<int K>
__global__ __launch_bounds__(256) void wfrag_kernel(
    const float* __restrict__ W, unsigned short* __restrict__ wfrag)
{
    constexpr int KS = K / 32;
    int idx = blockIdx.x * 256 + threadIdx.x;
    int total = RNUM * KS * 4 * 64;
    if (idx >= total) return;
    int lane = idx & 63;
    int tmp = idx >> 6;
    int jt = tmp & 3; tmp >>= 2;
    int ks = tmp % KS;
    int t = tmp / KS;
    int col = jt * 16 + (lane & 15);
    int kb = ks * 32 + (lane >> 4) * 8;
    const float* Wp = W + ((size_t)t * K + kb) * HD + col;
    uint4 o;
    o.x = pack2bf(Wp[0 * HD], Wp[1 * HD]);
    o.y = pack2bf(Wp[2 * HD], Wp[3 * HD]);
    o.z = pack2bf(Wp[4 * HD], Wp[5 * HD]);
    o.w = pack2bf(Wp[6 * HD], Wp[7 * HD]);
    *(uint4*)(wfrag + (size_t)idx * 8) = o;
}

// same fragment permute for a single matrix (Wroot)
template<int K>
__global__ __launch_bounds__(256) void wfroot_kernel(
    const float* __restrict__ Root, unsigned short* __restrict__ wfr)
{
    constexpr int KS = K / 32;
    int idx = blockIdx.x * 256 + threadIdx.x;
    int total = KS * 4 * 64;
    if (idx >= total) return;
    int lane = idx & 63;
    int tmp = idx >> 6;
    int jt = tmp & 3;
    int ks = tmp >> 2;
    int col = jt * 16 + (lane & 15);
    int kb = ks * 32 + (lane >> 4) * 8;
    const float* Wp = Root + (size_t)kb * HD + col;
    uint4 o;
    o.x = pack2bf(Wp[0 * HD], Wp[1 * HD]);
    o.y = pack2bf(Wp[2 * HD], Wp[3 * HD]);
    o.z = pack2bf(Wp[4 * HD], Wp[5 * HD]);
    o.w = pack2bf(Wp[6 * HD], Wp[7 * HD]);
    *(uint4*)(wfr + (size_t)idx * 8) = o;
}

// dense MFMA GEMM: hroot[n][j] = bias[j] + sum_k x[n][k]*Root[k][j]  (bf16 out)
template<int K>
__global__ __launch_bounds__(256) void rootmm_kernel(
    const unsigned short* __restrict__ xb, const unsigned short* __restrict__ wfr,
    const float* __restrict__ bias, unsigned short* __restrict__ hroot, int N)
{
    constexpr int KS = K / 32;
    __shared__ unsigned short sW[KS * 4 * 64 * 8];
    __shared__ float sbias[HD];
    const int tid = threadIdx.x;
    for (int i = tid; i < KS * 256; i += 256)
        ((uint4*)sW)[i] = ((const uint4*)wfr)[i];
    if (tid < HD) sbias[tid] = bias[tid];
    __syncthreads();
    const int lane = tid & 63;
    const int wid = tid >> 6;
    const int jb = (lane >> 4) * 4;
#pragma unroll
    for (int b = 0; b < 4; ++b) {
        const int node = blockIdx.x * 256 + wid * 64 + b * 16 + (lane & 15);
        const int nclamp = node < N ? node : N - 1;
        const unsigned short* xp = xb + (size_t)nclamp * K + (lane >> 4) * 8;
        f32x4 acc[4];
#pragma unroll
        for (int jt = 0; jt < 4; ++jt) acc[jt] = (f32x4)0.0f;
#pragma unroll
        for (int ks = 0; ks < KS; ++ks) {
            bf16x8 bx = *(const bf16x8*)(xp + ks * 32);
#pragma unroll
            for (int jt = 0; jt < 4; ++jt) {
                bf16x8 aw = *(const bf16x8*)(sW + (size_t)((ks * 4 + jt) * 64 + lane) * 8);
                acc[jt] = __builtin_amdgcn_mfma_f32_16x16x32_bf16(aw, bx, acc[jt], 0, 0, 0);
            }
        }
        if (node < N) {
            unsigned short* hr = hroot + (size_t)node * HD + jb;
#pragma unroll
            for (int jt = 0; jt < 4; ++jt) {
                const int j0 = jt * 16 + jb;
                uint2 pk;
                pk.x = pack2bf(acc[jt][0] + sbias[j0 + 0], acc[jt][1] + sbias[j0 + 1]);
                pk.y = pack2bf(acc[jt][2] + sbias[j0 + 2], acc[jt][3] + sbias[j0 + 3]);
                *(uint2*)(hr + jt * 16) = pk;
            }
        }
    }
}

// fused RGCN layer: 256 threads, ~40 KB LDS -> 4 blocks/CU (16 waves).
// Node-aligned window, in-LDS type sort (wave-parallel setup), depth-1
// gather pipeline, msg at sorted position (XOR swizzle), per-node segmented
// mean + hroot + relu. PL=1: layer-2 variant, fuses global mean-pool and
// skips the h write.
template<int K, int PL>
__global__ __launch_bounds__(256) void fused_kernel(
    const unsigned short* __restrict__ xb, const int* __restrict__ es,
    const int* __restrict__ nstart, const int* __restrict__ bstart,
    const unsigned short* __restrict__ wfrag,
    const unsigned short* __restrict__ hroot,
    unsigned short* __restrict__ hout,
    const int* __restrict__ batch, float* __restrict__ pool,
    float* __restrict__ gcnt, int col0)
{
    constexpr int KS = K / 32;
    __shared__ unsigned short msg[CAPE * HD];
    __shared__ int s_es[CAPE];
    __shared__ unsigned short s_idx[CAPE];      // sorted pos -> orig idx
    __shared__ unsigned short s_pos[CAPE];      // orig idx -> sorted pos
    __shared__ int hist[RNUM], tbase[RNUM], tcur[RNUM];
    __shared__ int bdesc[CAPE / 16 + RNUM + 2];
    __shared__ int nb_s, nend_s;
    __shared__ int scnt[4][RNUM];
    __shared__ float sinv[4][RNUM];

    const int tid = threadIdx.x, lane = tid & 63, wid = tid >> 6;
    int n0 = bstart[blockIdx.x];
    const int n1 = bstart[blockIdx.x + 1];

    while (n0 < n1) {
        // wave-0 cooperative greedy pack: nodes [n0, nend) with <= CAPE edges
        if (wid == 0) {
            const int ea_ = nstart[n0];
            int m = n0;
            for (;;) {
                int cand = m + 1 + lane;
                bool ok = (cand <= n1) && (nstart[cand] - ea_ <= CAPE);
                unsigned long long mm = __ballot(ok);
                int f = (~mm == 0ULL) ? 64 : (__ffsll((unsigned long long)(~mm)) - 1);
                m += f;
                if (f < 64 || m >= n1) break;
            }
            if (m == n0) m = n0 + 1;          // single node with deg > CAPE: clamp
            if (m > n1) m = n1;
            if (lane == 0) nend_s = m;
        }
        __syncthreads();
        const int na = n0, ne = nend_s;
        const int ea = nstart[na];
        int cnt = nstart[ne] - ea;
        if (cnt > CAPE) cnt = CAPE;

        // stage + type counting sort (int LDS atomics only)
        for (int i = tid; i < cnt; i += 256) s_es[i] = es[ea + i];
        if (tid < RNUM) hist[tid] = 0;
        __syncthreads();
        for (int i = tid; i < cnt; i += 256)
            atomicAdd(&hist[(s_es[i] >> 17) & 31], 1);
        __syncthreads();
        // wave-parallel tbase + bdesc build (lanes 0..31 of wave 0)
        if (wid == 0) {
            const int t = lane & 31;
            int h = (lane < RNUM) ? hist[t] : 0;
            int nbatch = (h + 15) >> 4;
            int ph = h, pb = nbatch;
            for (int off = 1; off < 32; off <<= 1) {
                int vh = __shfl_up(ph, off, 32);
                int vb = __shfl_up(pb, off, 32);
                if ((lane & 31) >= off) { ph += vh; pb += vb; }
            }
            if (lane < RNUM) {
                const int tb = ph - h;
                tbase[t] = tb;
                int bo = pb - nbatch;
                for (int c2 = 0; c2 < h; c2 += 16)
                    bdesc[bo++] = (t << 10) | (tb + c2);
                if (t == RNUM - 1) nb_s = pb;
            }
        }
        __syncthreads();
        if (tid < RNUM) tcur[tid] = tbase[tid];
        __syncthreads();
        for (int i = tid; i < cnt; i += 256) {
            int t = (s_es[i] >> 17) & 31;
            int pos = atomicAdd(&tcur[t], 1);
            s_idx[pos] = (unsigned short)i;
            s_pos[i] = (unsigned short)pos;
        }
        __syncthreads();

        // MFMA phase: 16-edge single-type batches, depth-1 prefetch pipeline
        {
            const int nbt = nb_s;
            const int b0 = (nbt * wid) >> 2;
            const int b1 = (nbt * (wid + 1)) >> 2;
            if (b0 < b1) {
                int c_c;
                bool val_c;
                const unsigned short* wt_c;
                bf16x8 bx_c[KS];
                {
                    const int desc = bdesc[b0];
                    const int t = desc >> 10;
                    const int p0 = desc & 1023;
                    const int tend = tbase[t] + hist[t];
                    c_c = p0 + (lane & 15);
                    val_c = c_c < tend;
                    wt_c = wfrag + (size_t)t * (KS * 2048);
                    const int idx = s_idx[val_c ? c_c : p0];
                    const unsigned short* xp =
                        xb + (size_t)(s_es[idx] & 0x1FFFF) * K + (lane >> 4) * 8;
#pragma unroll
                    for (int ks = 0; ks < KS; ++ks) bx_c[ks] = *(const bf16x8*)(xp + ks * 32);
                }
                for (int bi = b0; bi < b1; ++bi) {
                    int c_n = 0;
                    bool val_n = false;
                    const unsigned short* wt_n = wt_c;
                    bf16x8 bx_n[KS];
                    if (bi + 1 < b1) {
                        const int desc = bdesc[bi + 1];
                        const int t = desc >> 10;
                        const int p0 = desc & 1023;
                        const int tend = tbase[t] + hist[t];
                        c_n = p0 + (lane & 15);
                        val_n = c_n < tend;
                        wt_n = wfrag + (size_t)t * (KS * 2048);
                        const int idx = s_idx[val_n ? c_n : p0];
                        const unsigned short* xp =
                            xb + (size_t)(s_es[idx] & 0x1FFFF) * K + (lane >> 4) * 8;
#pragma unroll
                        for (int ks = 0; ks < KS; ++ks) bx_n[ks] = *(const bf16x8*)(xp + ks * 32);
                    }
                    f32x4 acc[4];
#pragma unroll
                    for (int jt = 0; jt < 4; ++jt) acc[jt] = (f32x4)0.0f;
#pragma unroll
                    for (int ks = 0; ks < KS; ++ks) {
#pragma unroll
                        for (int jt = 0; jt < 4; ++jt) {
                            bf16x8 aw = *(const bf16x8*)(wt_c + (size_t)((ks * 4 + jt) * 64 + lane) * 8);
                            acc[jt] = __builtin_amdgcn_mfma_f32_16x16x32_bf16(aw, bx_c[ks], acc[jt], 0, 0, 0);
                        }
                    }
                    if (val_c) {
                        char* mr = (char*)(msg + c_c * HD);
                        const int swz = (c_c & 7) << 4;
#pragma unroll
                        for (int jt = 0; jt < 4; ++jt) {
                            uint2 pk;
                            pk.x = pack2bf(acc[jt][0], acc[jt][1]);
                            pk.y = pack2bf(acc[jt][2], acc[jt][3]);
                            *(uint2*)(mr + (((lane >> 4) * 8 + jt * 32) ^ swz)) = pk;
                        }
                    }
                    c_c = c_n; val_c = val_n; wt_c = wt_n;
#pragma unroll
                    for (int ks = 0; ks < KS; ++ks) bx_c[ks] = bx_n[ks];
                }
            }
        }
        __syncthreads();

        // reduce phase
        if (PL) {
            // contiguous node range per wave; run-accumulate pool (batch sorted)
            const int NL = ne - na;
            const int ns = na + (NL * wid) / 4;
            const int nf = na + (NL * (wid + 1)) / 4;
            if (ns < nf) {
                int cur = batch[ns];
                float pacc = 0.f, pc = 0.f;
                for (int n = ns; n < nf; ++n) {
                    const int rs = nstart[n] - ea;
                    int re = nstart[n + 1] - ea;
                    if (re > cnt) re = cnt;
                    if (lane < RNUM) scnt[wid][lane] = 0;
                    for (int e = rs + lane; e < re; e += 64)
                        atomicAdd(&scnt[wid][(s_es[e] >> 17) & 31], 1);
                    if (lane < RNUM) {
                        int c = scnt[wid][lane];
                        sinv[wid][lane] = 1.0f / (float)(c > 1 ? c : 1);
                    }
                    float acc = b2f(hroot[(size_t)n * HD + lane]);
                    for (int e = rs; e < re; ++e) {
                        const float iv = sinv[wid][(s_es[e] >> 17) & 31];
                        const int row = s_pos[e];
                        const char* mr = (const char*)(msg + row * HD);
                        acc += iv * b2f(*(const unsigned short*)(mr + ((lane * 2) ^ ((row & 7) << 4))));
                    }
                    float rv = fmaxf(acc, 0.f);
                    int b = batch[n];
                    if (b != cur) {
                        unsafeAtomicAdd(&pool[(size_t)cur * 128 + col0 + lane], pacc);
                        if (lane == 0) unsafeAtomicAdd(&gcnt[cur], pc);
                        pacc = 0.f; pc = 0.f; cur = b;
                    }
                    pacc += rv;
                    pc += 1.f;
                }
                unsafeAtomicAdd(&pool[(size_t)cur * 128 + col0 + lane], pacc);
                if (lane == 0) unsafeAtomicAdd(&gcnt[cur], pc);
            }
        } else {
            for (int n = na + wid; n < ne; n += 4) {
                const int rs = nstart[n] - ea;
                int re = nstart[n + 1] - ea;
                if (re > cnt) re = cnt;
                if (lane < RNUM) scnt[wid][lane] = 0;
                for (int e = rs + lane; e < re; e += 64)
                    atomicAdd(&scnt[wid][(s_es[e] >> 17) & 31], 1);
                if (lane < RNUM) {
                    int c = scnt[wid][lane];
                    sinv[wid][lane] = 1.0f / (float)(c > 1 ? c : 1);
                }
                float acc = b2f(hroot[(size_t)n * HD + lane]);
                for (int e = rs; e < re; ++e) {
                    const float iv = sinv[wid][(s_es[e] >> 17) & 31];
                    const int row = s_pos[e];
                    const char* mr = (const char*)(msg + row * HD);
                    acc += iv * b2f(*(const unsigned short*)(mr + ((lane * 2) ^ ((row & 7) << 4))));
                }
                hout[(size_t)n * HD + lane] = f2b(fmaxf(acc, 0.f));
            }
        }
        __syncthreads();
        n0 = ne;
    }
}

__global__ __launch_bounds__(512) void depth_kernel(
    const float* __restrict__ depth, float* __restrict__ dnorm, int Bn)
{
    __shared__ float ls[8];
    __shared__ float smean, sstd;
    const int t = threadIdx.x, lane = t & 63, wv = t >> 6;
    float d = (t < Bn) ? depth[t] : 0.f;
    float s = d;
#pragma unroll
    for (int o = 32; o; o >>= 1) s += __shfl_down(s, o, 64);
    if (lane == 0) ls[wv] = s;
    __syncthreads();
    if (t == 0) {
        float tot = 0.f;
        for (int i = 0; i < 8; ++i) tot += ls[i];
        smean = tot / (float)Bn;
    }
    __syncthreads();
    float mean = smean;
    float df = (t < Bn) ? (d - mean) : 0.f;
    s = df * df;
#pragma unroll
    for (int o = 32; o; o >>= 1) s += __shfl_down(s, o, 64);
    __syncthreads();
    if (lane == 0) ls[wv] = s;
    __syncthreads();
    if (t == 0) {
        float tot = 0.f;
        for (int i = 0; i < 8; ++i) tot += ls[i];
        sstd = sqrtf(tot / (float)Bn);
    }
    __syncthreads();
    if (t < Bn) dnorm[t] = df / (sstd + 1e-6f);
}

__global__ __launch_bounds__(256) void regress_kernel(
    const float* __restrict__ pool, const float* __restrict__ gcnt_s,
    const float* __restrict__ gcnt_g, const float* __restrict__ dnorm,
    const float* __restrict__ rW1, const float* __restrict__ rB1,
    const float* __restrict__ rW2, const float* __restrict__ rB2,
    float* __restrict__ pred, int Bn)
{
    const int lane = threadIdx.x & 63;
    const int g = (blockIdx.x * 256 + threadIdx.x) >> 6;
    if (g >= Bn) return;
    const float is = 1.f / fmaxf(gcnt_s[g], 1.f);
    const float ig = 1.f / fmaxf(gcnt_g[g], 1.f);
    const float* pr = pool + (size_t)g * 128;
    float acc = rB1[lane];
    for (int k = 0; k < 64; ++k)
        acc = fmaf(pr[k] * is, rW1[k * 64 + lane], acc);
    for (int k = 64; k < 128; ++k)
        acc = fmaf(pr[k] * ig, rW1[k * 64 + lane], acc);
    acc = fmaf(dnorm[g], rW1[128 * 64 + lane], acc);
    float v = fmaxf(acc, 0.f) * rW2[lane];
#pragma unroll
    for (int o = 32; o; o >>= 1) v += __shfl_down(v, o, 64);
    if (lane == 0) pred[g] = v + rB2[0];
}

// ---------------- launch ----------------

extern "C" void kernel_launch(void* const* d_in, const int* in_sizes, int n_in,
                              void* d_out, int out_size, void* d_ws, size_t ws_size,
                              hipStream_t stream)
{
    const int E1 = in_sizes[2];
    const int E2 = in_sizes[6];
    const int Emax = E1 > E2 ? E1 : E2;
    const int N = in_sizes[3];
    const int IN = in_sizes[0] / N;   // 128
    const int Bn = in_sizes[8];

    const float* state_x = (const float*)d_in[0];
    const int* s_ei = (const int*)d_in[1];
    const int* s_et = (const int*)d_in[2];
    const int* s_batch = (const int*)d_in[3];
    const float* goal_x = (const float*)d_in[4];
    const int* g_ei = (const int*)d_in[5];
    const int* g_et = (const int*)d_in[6];
    const int* g_batch = (const int*)d_in[7];
    const float* depth = (const float*)d_in[8];
    const float* sW1 = (const float*)d_in[9];
    const float* sRoot1 = (const float*)d_in[10];
    const float* sB1 = (const float*)d_in[11];
    const float* sW2 = (const float*)d_in[12];
    const float* sRoot2 = (const float*)d_in[13];
    const float* sB2 = (const float*)d_in[14];
    const float* gW1 = (const float*)d_in[15];
    const float* gRoot1 = (const float*)d_in[16];
    const float* gB1 = (const float*)d_in[17];
    const float* gW2 = (const float*)d_in[18];
    const float* gRoot2 = (const float*)d_in[19];
    const float* gB2 = (const float*)d_in[20];
    const float* rW1 = (const float*)d_in[21];
    const float* rB1 = (const float*)d_in[22];
    const float* rW2 = (const float*)d_in[23];
    const float* rB2 = (const float*)d_in[24];
    float* pred = (float*)d_out;

    const int nbScan = (N + 1023) / 1024;
    const int nblkMax = (Emax + STRIDE - 1) / STRIDE;

    char* p = (char*)d_ws;
    auto alloc = [&](size_t bytes) { char* r = p; p += WS_ALIGN(bytes); return r; };
    int* deg    = (int*)alloc((size_t)N * 4);
    int* nstart = (int*)alloc((size_t)(N + 1) * 4);
    int* rank   = (int*)alloc((size_t)Emax * 4);
    int* part   = (int*)alloc((size_t)nbScan * 4);
    int* bstart = (int*)alloc((size_t)(nblkMax + 1) * 4);
    int* es     = (int*)alloc((size_t)Emax * 4);
    unsigned short* xb    = (unsigned short*)alloc((size_t)N * IN * 2);
    unsigned short* h1    = (unsigned short*)alloc((size_t)N * HD * 2);
    unsigned short* hroot = (unsigned short*)alloc((size_t)N * HD * 2);
    unsigned short* wf1   = (unsigned short*)alloc((size_t)RNUM * 4 * 4 * 64 * 8 * 2);
    unsigned short* wf2   = (unsigned short*)alloc((size_t)RNUM * 2 * 4 * 64 * 8 * 2);
    unsigned short* wfr1  = (unsigned short*)alloc((size_t)4 * 4 * 64 * 8 * 2);
    unsigned short* wfr2  = (unsigned short*)alloc((size_t)2 * 4 * 64 * 8 * 2);
    float* pool   = (float*)alloc((size_t)Bn * 128 * 4);
    float* gcnt_s = (float*)alloc((size_t)Bn * 4);
    float* gcnt_g = (float*)alloc((size_t)Bn * 4);
    float* dnorm  = (float*)alloc((size_t)Bn * 4);

    hipMemsetAsync(pool, 0, (size_t)Bn * 128 * 4, stream);
    hipMemsetAsync(gcnt_s, 0, (size_t)Bn * 4, stream);
    hipMemsetAsync(gcnt_g, 0, (size_t)Bn * 4, stream);

    const int nmmB = (N + 255) / 256;

    for (int enc = 0; enc < 2; ++enc) {
        const float* x = enc ? goal_x : state_x;
        const int* ei = enc ? g_ei : s_ei;
        const int* et = enc ? g_et : s_et;
        const int* batch = enc ? g_batch : s_batch;
        const float* W1 = enc ? gW1 : sW1;
        const float* Root1 = enc ? gRoot1 : sRoot1;
        const float* B1 = enc ? gB1 : sB1;
        const float* W2 = enc ? gW2 : sW2;
        const float* Root2 = enc ? gRoot2 : sRoot2;
        const float* B2 = enc ? gB2 : sB2;
        float* gcnt = enc ? gcnt_g : gcnt_s;
        const int E = enc ? E2 : E1;
        const int* srcp = ei;
        const int* dstp = ei + E;
        const int ebl = (E + 255) / 256;
        const int nblk = (E + STRIDE - 1) / STRIDE;

        hipMemsetAsync(deg, 0, (size_t)N * 4, stream);

        count_kernel<<<ebl, 256, 0, stream>>>(dstp, deg, rank, E);
        scan1_kernel<<<nbScan, 256, 0, stream>>>(deg, nstart, part, N);
        scan2_kernel<<<1, 64, 0, stream>>>(part, nbScan, nstart, N);
        scan3_kernel<<<nbScan * 4, 256, 0, stream>>>(nstart, part, N);
        boundary_kernel<<<(nblk + 1 + 255) / 256, 256, 0, stream>>>(nstart, bstart, N, nblk);
        scatter_kernel<<<ebl, 256, 0, stream>>>(srcp, dstp, et, rank, nstart, es, E);

        tobf16_kernel<<<(N * IN / 8 + 255) / 256, 256, 0, stream>>>(x, xb, N * IN / 8);
        wfrag_kernel<128><<<(RNUM * 4 * 4 * 64 + 255) / 256, 256, 0, stream>>>(W1, wf1);
        wfrag_kernel<64><<<(RNUM * 2 * 4 * 64 + 255) / 256, 256, 0, stream>>>(W2, wf2);
        wfroot_kernel<128><<<(4 * 4 * 64 + 255) / 256, 256, 0, stream>>>(Root1, wfr1);
        wfroot_kernel<64><<<(2 * 4 * 64 + 255) / 256, 256, 0, stream>>>(Root2, wfr2);

        // layer 1
        rootmm_kernel<128><<<nmmB, 256, 0, stream>>>(xb, wfr1, B1, hroot, N);
        fused_kernel<128, 0><<<nblk, 256, 0, stream>>>(
            xb, es, nstart, bstart, wf1, hroot, h1, nullptr, nullptr, nullptr, 0);
        // layer 2 (pool fused; no h2 write)
        rootmm_kernel<64><<<nmmB, 256, 0, stream>>>(h1, wfr2, B2, hroot, N);
        fused_kernel<64, 1><<<nblk, 256, 0, stream>>>(
            h1, es, nstart, bstart, wf2, hroot, nullptr, batch, pool, gcnt, enc * 64);
    }

    depth_kernel<<<1, 512, 0, stream>>>(depth, dnorm, Bn);
    regress_kernel<<<(Bn * 64 + 255) / 256, 256, 0, stream>>>(
        pool, gcnt_s, gcnt_g, dnorm, rW1, rB1, rW2, rB2, pred, Bn);
}